// Round 4
// baseline (208.873 us; speedup 1.0000x reference)
//
#include <hip/hip_runtime.h>
#include <hip/hip_bf16.h>
#include <stdint.h>

#define T_LEN 8192
#define DIN   1024
#define DOUT  1024
#define TRACE 64
#define CTX   16
#define KTOT  3072      // DIN + 2*TRACE*CTX
#define CH    64        // scan chunk length
#define NCHUNK 128      // T_LEN / CH

using bf16 = __hip_bfloat16;
typedef __attribute__((ext_vector_type(4))) float f32x4;
typedef __attribute__((ext_vector_type(8))) short s16x8;

__device__ __forceinline__ void pack4(const float4 v, void* dst) {
    union { bf16 h[4]; uint2 u; } pk;
    pk.h[0] = __float2bfloat16(v.x); pk.h[1] = __float2bfloat16(v.y);
    pk.h[2] = __float2bfloat16(v.z); pk.h[3] = __float2bfloat16(v.w);
    *(uint2*)dst = pk.u;
}

// ---------------- fused f32 -> bf16 conversions (x, W_skip, W_mix, W_pre) ----------------
// quads: x 2097152 | W_skip 262144 | W_mix 524288 | W_pre 16384  (total 2899968)
__global__ void cvt_all(const float* __restrict__ x, const float* __restrict__ Wsk,
                        const float* __restrict__ Wmx, const float* __restrict__ Wpre,
                        bf16* __restrict__ A, bf16* __restrict__ Bc, bf16* __restrict__ Wp) {
    int idx = blockIdx.x * 256 + threadIdx.x;
    if (idx < 2097152) {                       // x: 8192x1024 -> A (ld 3072)
        int r = idx >> 8, c4 = (idx & 255) << 2;
        pack4(*(const float4*)(x + (size_t)r * 1024 + c4), A + (size_t)r * KTOT + c4);
    } else if (idx < 2359296) {                // W_skip: 1024x1024 -> Bc (ld 3072, coff 0)
        int i = idx - 2097152;
        int r = i >> 8, c4 = (i & 255) << 2;
        pack4(*(const float4*)(Wsk + (size_t)r * 1024 + c4), Bc + (size_t)r * KTOT + c4);
    } else if (idx < 2883584) {                // W_mix: 1024x2048 -> Bc (ld 3072, coff 1024)
        int i = idx - 2359296;
        int r = i >> 9, c4 = (i & 511) << 2;
        pack4(*(const float4*)(Wmx + (size_t)r * 2048 + c4), Bc + (size_t)r * KTOT + 1024 + c4);
    } else if (idx < 2899968) {                // W_pre: 64x1024 -> Wp (ld 1024)
        int i = idx - 2883584;
        int r = i >> 8, c4 = (i & 255) << 2;
        pack4(*(const float4*)(Wpre + (size_t)r * 1024 + c4), Wp + (size_t)r * 1024 + c4);
    }
}

// ---------------- fused pre-GEMM + scan phase 1 ----------------
// One block per 64-row scan chunk. MFMA computes pre = x@W_pre^T + b_pre into LDS,
// then row-norms + local (zero-init) complex scan -> local_end / reset_any.
__global__ __launch_bounds__(256) void pre_scan1(
    const bf16* __restrict__ A,     // [8192][KTOT], x part (k<1024)
    const bf16* __restrict__ Wp,    // [64][1024]
    const float* __restrict__ bpre,
    const int* __restrict__ start,
    const float* __restrict__ a, const float* __restrict__ bfreq,
    float* __restrict__ pre_raw,    // [8192][64]
    float2* __restrict__ local_end, // [128][1024]
    int* __restrict__ reset_any) {  // [128]
    __shared__ short As[2][64 * 32];
    __shared__ short Bs[2][64 * 32];
    __shared__ float pn[CH][TRACE + 1];
    __shared__ float rn[CH];
    __shared__ int sf[CH];
    const int tid = threadIdx.x, lane = tid & 63, wv = tid >> 6;
    const int row0 = blockIdx.x * 64;
    const int l4 = lane >> 2, c8 = (lane & 3) * 8;

    auto stage = [&](int kt, int buf) {
        int r = wv * 16 + l4;
        const bf16* ga = A + (size_t)(row0 + r) * KTOT + kt * 32 + c8;
        const bf16* gb = Wp + (size_t)r * 1024 + kt * 32 + c8;
        __builtin_amdgcn_global_load_lds(
            (const __attribute__((address_space(1))) void*)ga,
            (__attribute__((address_space(3))) void*)&As[buf][wv * 512], 16, 0, 0);
        __builtin_amdgcn_global_load_lds(
            (const __attribute__((address_space(1))) void*)gb,
            (__attribute__((address_space(3))) void*)&Bs[buf][wv * 512], 16, 0, 0);
    };

    f32x4 acc[4];
#pragma unroll
    for (int j = 0; j < 4; ++j) acc[j] = (f32x4)0.0f;

    stage(0, 0);
    __syncthreads();
    int buf = 0;
    const int lr = lane & 15, lk = (lane >> 4) * 8;
    for (int kt = 0; kt < 32; ++kt) {
        if (kt + 1 < 32) stage(kt + 1, buf ^ 1);
        s16x8 af = *(const s16x8*)&As[buf][(wv * 16 + lr) * 32 + lk];
        s16x8 bfr[4];
#pragma unroll
        for (int j = 0; j < 4; ++j)
            bfr[j] = *(const s16x8*)&Bs[buf][(j * 16 + lr) * 32 + lk];
#pragma unroll
        for (int j = 0; j < 4; ++j)
            acc[j] = __builtin_amdgcn_mfma_f32_16x16x32_bf16(af, bfr[j], acc[j], 0, 0, 0);
        __syncthreads();
        buf ^= 1;
    }
    // epilogue: C layout col=lane&15, row=(lane>>4)*4+reg
    const int lg = lane >> 4;
#pragma unroll
    for (int j = 0; j < 4; ++j) {
        int col = j * 16 + lr;
        float bias = bpre[col];
#pragma unroll
        for (int r = 0; r < 4; ++r) {
            int rl = wv * 16 + lg * 4 + r;
            float v = acc[j][r] + bias;
            pn[rl][col] = v;
            pre_raw[(size_t)(row0 + rl) * TRACE + col] = v;
        }
    }
    if (tid < CH) sf[tid] = start[row0 + tid];
    __syncthreads();
    if (tid < CH) {
        float s = 0.f;
#pragma unroll
        for (int m = 0; m < TRACE; ++m) { float v = pn[tid][m]; s += v * v; }
        rn[tid] = 1.0f / (1e-6f + sqrtf(s));
        int any = __any(sf[tid] != 0);
        if (tid == 0) reset_any[blockIdx.x] = any;
    }
    __syncthreads();
#pragma unroll
    for (int q = 0; q < 4; ++q) {
        int pair = tid + q * 256;
        int m = pair >> 4, c = pair & 15;
        float am = a[m], th = bfreq[c];
        float e = expf(-fabsf(am));
        float sn, cs; sincosf(th, &sn, &cs);
        float gr = e * cs, gi = e * sn;
        float sre = 0.f, sim = 0.f;
        for (int r = 0; r < CH; ++r) {
            float p = pn[r][m] * rn[r];
            if (sf[r]) { sre = p; sim = 0.f; }
            else { float t = gr * sre - gi * sim + p; sim = gr * sim + gi * sre; sre = t; }
        }
        local_end[(size_t)blockIdx.x * 1024 + pair] = make_float2(sre, sim);
    }
}

// ---------------- scan phase 2: sequential carry over chunks ----------------
// Tail layout: PLANAR — out_tail[0..1023] = re(m*16+c), out_tail[1024..2047] = im.
__global__ void scan_phase2(const float2* __restrict__ local_end, const int* __restrict__ reset_any,
                            const float* __restrict__ state_re, const float* __restrict__ state_im,
                            const float* __restrict__ a, const float* __restrict__ bfreq,
                            float2* __restrict__ carry_in, float* __restrict__ out_tail, int tail_n) {
    const int pair = threadIdx.x;  // 1024 threads
    const int m = pair >> 4, c = pair & 15;
    float am = a[m], th = bfreq[c];
    float e = expf(-64.f * fabsf(am));
    float sn, cs; sincosf(64.f * th, &sn, &cs);
    float gr = e * cs, gi = e * sn;
    float cre = state_re[pair], cim = state_im[pair];
    for (int k = 0; k < NCHUNK; ++k) {
        carry_in[(size_t)k * 1024 + pair] = make_float2(cre, cim);
        float2 le = local_end[(size_t)k * 1024 + pair];
        if (reset_any[k]) { cre = le.x; cim = le.y; }
        else {
            float t = gr * cre - gi * cim + le.x;
            cim = gr * cim + gi * cre + le.y;
            cre = t;
        }
    }
    if (pair < tail_n)        out_tail[pair]        = cre;
    if (1024 + pair < tail_n) out_tail[1024 + pair] = cim;
}

// ---------------- scan phase 3: recompute with carry, emit bf16 z_in ----------------
__global__ void scan_phase3(const float* __restrict__ pre_raw, const int* __restrict__ start,
                            const float* __restrict__ a, const float* __restrict__ bfreq,
                            const float2* __restrict__ carry_in, bf16* __restrict__ A) {
    __shared__ float pn[CH][TRACE + 1];
    __shared__ float rn[CH];
    __shared__ int sf[CH];
    const int k = blockIdx.x, tid = threadIdx.x;
    for (int idx = tid; idx < CH * TRACE; idx += 256) {
        int r = idx >> 6, m = idx & 63;
        pn[r][m] = pre_raw[(size_t)(k * CH + r) * TRACE + m];
    }
    if (tid < CH) sf[tid] = start[k * CH + tid];
    __syncthreads();
    if (tid < CH) {
        float s = 0.f;
#pragma unroll
        for (int m = 0; m < TRACE; ++m) { float v = pn[tid][m]; s += v * v; }
        rn[tid] = 1.0f / (1e-6f + sqrtf(s));
    }
    __syncthreads();
#pragma unroll
    for (int q = 0; q < 4; ++q) {
        int pair = tid + q * 256;
        int m = pair >> 4, c = pair & 15;
        float am = a[m], th = bfreq[c];
        float e = expf(-fabsf(am));
        float sn, cs; sincosf(th, &sn, &cs);
        float gr = e * cs, gi = e * sn;
        float2 ci = carry_in[(size_t)k * 1024 + pair];
        float sre = ci.x, sim = ci.y;
        for (int r = 0; r < CH; ++r) {
            float p = pn[r][m] * rn[r];
            if (sf[r]) { sre = p; sim = 0.f; }
            else { float t = gr * sre - gi * sim + p; sim = gr * sim + gi * sre; sre = t; }
            size_t rowoff = (size_t)(k * CH + r) * KTOT;
            A[rowoff + 1024 + m * 32 + c]      = __float2bfloat16(sre);
            A[rowoff + 1024 + m * 32 + 16 + c] = __float2bfloat16(sim);
        }
    }
}

// ---------------- main GEMM: out = [x|z] @ [W_skip|W_mix]^T + bias ----------------
// 128x64 tile, BK=32, global_load_lds width-16, 2-phase loop, grid 1024 = 4 blocks/CU.
// Swizzle: each XCD gets 2 col-tiles (B-panel 786 KB -> L2-resident) x all 64 row-tiles.
__global__ __launch_bounds__(256) void gemm_main(const bf16* __restrict__ A,  // [8192][3072]
                                                 const bf16* __restrict__ B,  // [1024][3072]
                                                 const float* __restrict__ bskip,
                                                 const float* __restrict__ bmix,
                                                 float* __restrict__ out) {   // [8192][1024]
    __shared__ short As[2][128 * 32];
    __shared__ short Bs[2][64 * 32];
    const int tid = threadIdx.x;
    const int lane = tid & 63, wv = tid >> 6;
    const int wm = wv >> 1, wn = wv & 1;

    const int wg  = blockIdx.x;
    const int swz = (wg & 7) * 128 + (wg >> 3);   // 1024 blocks, bijective
    const int row0 = (swz & 63) * 128;            // 64 row tiles
    const int col0 = (swz >> 6) * 64;             // 16 col tiles

    const int l4 = lane >> 2;
    const int c8 = (lane & 3) * 8;

    auto stage = [&](int kt, int buf) {
#pragma unroll
        for (int j = 0; j < 2; ++j) {
            int chunk = wv * 2 + j;               // A: 8 chunks of 16 rows
            int r = chunk * 16 + l4;
            const bf16* ga = A + (size_t)(row0 + r) * KTOT + kt * 32 + c8;
            __builtin_amdgcn_global_load_lds(
                (const __attribute__((address_space(1))) void*)ga,
                (__attribute__((address_space(3))) void*)&As[buf][chunk * 512], 16, 0, 0);
        }
        int rB = wv * 16 + l4;                    // B: 4 chunks of 16 rows
        const bf16* gb = B + (size_t)(col0 + rB) * KTOT + kt * 32 + c8;
        __builtin_amdgcn_global_load_lds(
            (const __attribute__((address_space(1))) void*)gb,
            (__attribute__((address_space(3))) void*)&Bs[buf][wv * 512], 16, 0, 0);
    };

    f32x4 acc[4][2];
#pragma unroll
    for (int i = 0; i < 4; ++i)
#pragma unroll
        for (int j = 0; j < 2; ++j) acc[i][j] = (f32x4)0.0f;

    stage(0, 0);
    __syncthreads();
    int buf = 0;
    const int lr = lane & 15, lk = (lane >> 4) * 8;
    const int NT = KTOT / 32;  // 96
    for (int kt = 0; kt < NT; ++kt) {
        if (kt + 1 < NT) stage(kt + 1, buf ^ 1);
        s16x8 af[4], bfr[2];
#pragma unroll
        for (int i = 0; i < 4; ++i)
            af[i] = *(const s16x8*)&As[buf][(wm * 64 + i * 16 + lr) * 32 + lk];
#pragma unroll
        for (int j = 0; j < 2; ++j)
            bfr[j] = *(const s16x8*)&Bs[buf][(wn * 32 + j * 16 + lr) * 32 + lk];
#pragma unroll
        for (int i = 0; i < 4; ++i)
#pragma unroll
            for (int j = 0; j < 2; ++j)
                acc[i][j] = __builtin_amdgcn_mfma_f32_16x16x32_bf16(af[i], bfr[j], acc[i][j], 0, 0, 0);
        __syncthreads();
        buf ^= 1;
    }
    const int lg = lane >> 4;
#pragma unroll
    for (int j = 0; j < 2; ++j) {
        int col = col0 + wn * 32 + j * 16 + lr;
        float bias = bskip[col] + bmix[col];
#pragma unroll
        for (int i = 0; i < 4; ++i) {
            int rbase = row0 + wm * 64 + i * 16 + lg * 4;
#pragma unroll
            for (int r = 0; r < 4; ++r)
                out[(size_t)(rbase + r) * DOUT + col] = acc[i][j][r] + bias;
        }
    }
}

extern "C" void kernel_launch(void* const* d_in, const int* in_sizes, int n_in,
                              void* d_out, int out_size, void* d_ws, size_t ws_size,
                              hipStream_t stream) {
    const float* x        = (const float*)d_in[0];
    const float* state_re = (const float*)d_in[1];
    const float* state_im = (const float*)d_in[2];
    const int*   start    = (const int*)d_in[3];
    const float* W_pre    = (const float*)d_in[5];
    const float* b_pre    = (const float*)d_in[6];
    const float* W_skip   = (const float*)d_in[7];
    const float* b_skip   = (const float*)d_in[8];
    const float* W_mix    = (const float*)d_in[9];
    const float* b_mix    = (const float*)d_in[10];
    const float* a_dec    = (const float*)d_in[11];
    const float* b_freq   = (const float*)d_in[12];

    uint8_t* ws = (uint8_t*)d_ws;
    bf16*  A         = (bf16*)(ws);                 // 8192*3072*2 = 50331648
    bf16*  Bc        = (bf16*)(ws + 50331648);      // 1024*3072*2 = 6291456
    bf16*  Wp        = (bf16*)(ws + 56623104);      // 64*1024*2   = 131072
    float* pre_raw   = (float*)(ws + 56754176);     // 8192*64*4   = 2097152
    float2* local_end= (float2*)(ws + 58851328);    // 128*1024*8  = 1048576
    float2* carry_in = (float2*)(ws + 59899904);    // 1048576
    int*   reset_any = (int*)(ws + 60948480);       // 512

    cvt_all<<<dim3((2899968 + 255) / 256), 256, 0, stream>>>(x, W_skip, W_mix, W_pre, A, Bc, Wp);

    pre_scan1<<<dim3(NCHUNK), 256, 0, stream>>>(A, Wp, b_pre, start, a_dec, b_freq,
                                                pre_raw, local_end, reset_any);
    int tail_n = out_size - 8192 * 1024;
    if (tail_n < 0) tail_n = 0;
    if (tail_n > 2048) tail_n = 2048;
    scan_phase2<<<dim3(1), 1024, 0, stream>>>(local_end, reset_any, state_re, state_im, a_dec, b_freq,
                                              carry_in, (float*)d_out + 8192 * 1024, tail_n);
    scan_phase3<<<dim3(NCHUNK), 256, 0, stream>>>(pre_raw, start, a_dec, b_freq, carry_in, A);
    gemm_main<<<dim3(1024), 256, 0, stream>>>(A, Bc, b_skip, b_mix, (float*)d_out);
}

// Round 5
// 186.109 us; speedup vs baseline: 1.1223x; 1.1223x over previous
//
#include <hip/hip_runtime.h>
#include <hip/hip_bf16.h>
#include <stdint.h>

#define T_LEN 8192
#define DIN   1024
#define DOUT  1024
#define TRACE 64
#define CTX   16
#define KTOT  3072      // DIN + 2*TRACE*CTX
#define CH    64        // scan chunk length
#define NCHUNK 128      // T_LEN / CH

using bf16 = __hip_bfloat16;
typedef __attribute__((ext_vector_type(4))) float f32x4;
typedef __attribute__((ext_vector_type(8))) short s16x8;

__device__ __forceinline__ void pack4(const float4 v, void* dst) {
    union { bf16 h[4]; uint2 u; } pk;
    pk.h[0] = __float2bfloat16(v.x); pk.h[1] = __float2bfloat16(v.y);
    pk.h[2] = __float2bfloat16(v.z); pk.h[3] = __float2bfloat16(v.w);
    *(uint2*)dst = pk.u;
}

// ---------------- fused f32 -> bf16 conversions (x, W_skip, W_mix, W_pre) ----------------
__global__ void cvt_all(const float* __restrict__ x, const float* __restrict__ Wsk,
                        const float* __restrict__ Wmx, const float* __restrict__ Wpre,
                        bf16* __restrict__ A, bf16* __restrict__ Bc, bf16* __restrict__ Wp) {
    int idx = blockIdx.x * 256 + threadIdx.x;
    if (idx < 2097152) {                       // x: 8192x1024 -> A (ld 3072)
        int r = idx >> 8, c4 = (idx & 255) << 2;
        pack4(*(const float4*)(x + (size_t)r * 1024 + c4), A + (size_t)r * KTOT + c4);
    } else if (idx < 2359296) {                // W_skip: 1024x1024 -> Bc (ld 3072, coff 0)
        int i = idx - 2097152;
        int r = i >> 8, c4 = (i & 255) << 2;
        pack4(*(const float4*)(Wsk + (size_t)r * 1024 + c4), Bc + (size_t)r * KTOT + c4);
    } else if (idx < 2883584) {                // W_mix: 1024x2048 -> Bc (ld 3072, coff 1024)
        int i = idx - 2359296;
        int r = i >> 9, c4 = (i & 511) << 2;
        pack4(*(const float4*)(Wmx + (size_t)r * 2048 + c4), Bc + (size_t)r * KTOT + 1024 + c4);
    } else if (idx < 2899968) {                // W_pre: 64x1024 -> Wp (ld 1024)
        int i = idx - 2883584;
        int r = i >> 8, c4 = (i & 255) << 2;
        pack4(*(const float4*)(Wpre + (size_t)r * 1024 + c4), Wp + (size_t)r * 1024 + c4);
    }
}

// ---------------- fused pre-GEMM + scan phase 1 ----------------
__global__ __launch_bounds__(256) void pre_scan1(
    const bf16* __restrict__ A,     // [8192][KTOT], x part (k<1024)
    const bf16* __restrict__ Wp,    // [64][1024]
    const float* __restrict__ bpre,
    const int* __restrict__ start,
    const float* __restrict__ a, const float* __restrict__ bfreq,
    float* __restrict__ pre_raw,    // [8192][64]
    float2* __restrict__ local_end, // [128][1024]
    int* __restrict__ reset_any) {  // [128]
    __shared__ short As[2][64 * 32];
    __shared__ short Bs[2][64 * 32];
    __shared__ float pn[CH][TRACE + 1];
    __shared__ float rn[CH];
    __shared__ int sf[CH];
    const int tid = threadIdx.x, lane = tid & 63, wv = tid >> 6;
    const int row0 = blockIdx.x * 64;
    const int l4 = lane >> 2, c8 = (lane & 3) * 8;

    auto stage = [&](int kt, int buf) {
        int r = wv * 16 + l4;
        const bf16* ga = A + (size_t)(row0 + r) * KTOT + kt * 32 + c8;
        const bf16* gb = Wp + (size_t)r * 1024 + kt * 32 + c8;
        __builtin_amdgcn_global_load_lds(
            (const __attribute__((address_space(1))) void*)ga,
            (__attribute__((address_space(3))) void*)&As[buf][wv * 512], 16, 0, 0);
        __builtin_amdgcn_global_load_lds(
            (const __attribute__((address_space(1))) void*)gb,
            (__attribute__((address_space(3))) void*)&Bs[buf][wv * 512], 16, 0, 0);
    };

    f32x4 acc[4];
#pragma unroll
    for (int j = 0; j < 4; ++j) acc[j] = (f32x4)0.0f;

    stage(0, 0);
    __syncthreads();
    int buf = 0;
    const int lr = lane & 15, lk = (lane >> 4) * 8;
    for (int kt = 0; kt < 32; ++kt) {
        if (kt + 1 < 32) stage(kt + 1, buf ^ 1);
        s16x8 af = *(const s16x8*)&As[buf][(wv * 16 + lr) * 32 + lk];
        s16x8 bfr[4];
#pragma unroll
        for (int j = 0; j < 4; ++j)
            bfr[j] = *(const s16x8*)&Bs[buf][(j * 16 + lr) * 32 + lk];
#pragma unroll
        for (int j = 0; j < 4; ++j)
            acc[j] = __builtin_amdgcn_mfma_f32_16x16x32_bf16(af, bfr[j], acc[j], 0, 0, 0);
        __syncthreads();
        buf ^= 1;
    }
    const int lg = lane >> 4;
#pragma unroll
    for (int j = 0; j < 4; ++j) {
        int col = j * 16 + lr;
        float bias = bpre[col];
#pragma unroll
        for (int r = 0; r < 4; ++r) {
            int rl = wv * 16 + lg * 4 + r;
            float v = acc[j][r] + bias;
            pn[rl][col] = v;
            pre_raw[(size_t)(row0 + rl) * TRACE + col] = v;
        }
    }
    if (tid < CH) sf[tid] = start[row0 + tid];
    __syncthreads();
    if (tid < CH) {
        float s = 0.f;
#pragma unroll
        for (int m = 0; m < TRACE; ++m) { float v = pn[tid][m]; s += v * v; }
        rn[tid] = 1.0f / (1e-6f + sqrtf(s));
        int any = __any(sf[tid] != 0);
        if (tid == 0) reset_any[blockIdx.x] = any;
    }
    __syncthreads();
#pragma unroll
    for (int q = 0; q < 4; ++q) {
        int pair = tid + q * 256;
        int m = pair >> 4, c = pair & 15;
        float am = a[m], th = bfreq[c];
        float e = expf(-fabsf(am));
        float sn, cs; sincosf(th, &sn, &cs);
        float gr = e * cs, gi = e * sn;
        float sre = 0.f, sim = 0.f;
        for (int r = 0; r < CH; ++r) {
            float p = pn[r][m] * rn[r];
            if (sf[r]) { sre = p; sim = 0.f; }
            else { float t = gr * sre - gi * sim + p; sim = gr * sim + gi * sre; sre = t; }
        }
        local_end[(size_t)blockIdx.x * 1024 + pair] = make_float2(sre, sim);
    }
}

// ---------------- scan phase 2: sequential carry, 8-deep prefetch ----------------
// Tail layout: PLANAR — out_tail[0..1023] = re, out_tail[1024..2047] = im.
__global__ void scan_phase2(const float2* __restrict__ local_end, const int* __restrict__ reset_any,
                            const float* __restrict__ state_re, const float* __restrict__ state_im,
                            const float* __restrict__ a, const float* __restrict__ bfreq,
                            float2* __restrict__ carry_in, float* __restrict__ out_tail, int tail_n) {
    const int pair = threadIdx.x;  // 1024 threads
    const int m = pair >> 4, c = pair & 15;
    float am = a[m], th = bfreq[c];
    float e = expf(-64.f * fabsf(am));
    float sn, cs; sincosf(64.f * th, &sn, &cs);
    float gr = e * cs, gi = e * sn;
    float cre = state_re[pair], cim = state_im[pair];

    float2 pf[8]; int rsv[8];
#pragma unroll
    for (int j = 0; j < 8; ++j) { pf[j] = local_end[(size_t)j * 1024 + pair]; rsv[j] = reset_any[j]; }
    for (int kb = 0; kb < NCHUNK; kb += 8) {
        float2 cur[8]; int rs[8];
#pragma unroll
        for (int j = 0; j < 8; ++j) { cur[j] = pf[j]; rs[j] = rsv[j]; }
        if (kb + 8 < NCHUNK) {
#pragma unroll
            for (int j = 0; j < 8; ++j) {
                pf[j]  = local_end[(size_t)(kb + 8 + j) * 1024 + pair];
                rsv[j] = reset_any[kb + 8 + j];
            }
        }
#pragma unroll
        for (int j = 0; j < 8; ++j) {
            carry_in[(size_t)(kb + j) * 1024 + pair] = make_float2(cre, cim);
            if (rs[j]) { cre = cur[j].x; cim = cur[j].y; }
            else {
                float t = gr * cre - gi * cim + cur[j].x;
                cim = gr * cim + gi * cre + cur[j].y;
                cre = t;
            }
        }
    }
    if (pair < tail_n)        out_tail[pair]        = cre;
    if (1024 + pair < tail_n) out_tail[1024 + pair] = cim;
}

// ---------------- scan phase 3: recompute with carry, emit bf16 z_in (4B stores) ----------------
__global__ void scan_phase3(const float* __restrict__ pre_raw, const int* __restrict__ start,
                            const float* __restrict__ a, const float* __restrict__ bfreq,
                            const float2* __restrict__ carry_in, bf16* __restrict__ A) {
    __shared__ float pn[CH][TRACE + 1];
    __shared__ float rn[CH];
    __shared__ int sf[CH];
    const int k = blockIdx.x, tid = threadIdx.x;
    for (int idx = tid; idx < CH * TRACE; idx += 256) {
        int r = idx >> 6, m = idx & 63;
        pn[r][m] = pre_raw[(size_t)(k * CH + r) * TRACE + m];
    }
    if (tid < CH) sf[tid] = start[k * CH + tid];
    __syncthreads();
    if (tid < CH) {
        float s = 0.f;
#pragma unroll
        for (int m = 0; m < TRACE; ++m) { float v = pn[tid][m]; s += v * v; }
        rn[tid] = 1.0f / (1e-6f + sqrtf(s));
    }
    __syncthreads();
#pragma unroll
    for (int q = 0; q < 2; ++q) {
        int p0 = q * 512 + tid * 2;           // even pair: handles (m, c0) and (m, c0+1)
        int m = p0 >> 4, c0 = p0 & 15;
        float am = a[m];
        float e = expf(-fabsf(am));
        float sn0, cs0, sn1, cs1;
        sincosf(bfreq[c0], &sn0, &cs0);
        sincosf(bfreq[c0 + 1], &sn1, &cs1);
        float gr0 = e * cs0, gi0 = e * sn0;
        float gr1 = e * cs1, gi1 = e * sn1;
        float4 ci = *(const float4*)&carry_in[(size_t)k * 1024 + p0];
        float sre0 = ci.x, sim0 = ci.y, sre1 = ci.z, sim1 = ci.w;
        for (int r = 0; r < CH; ++r) {
            float p = pn[r][m] * rn[r];
            if (sf[r]) { sre0 = p; sim0 = 0.f; sre1 = p; sim1 = 0.f; }
            else {
                float t0 = gr0 * sre0 - gi0 * sim0 + p; sim0 = gr0 * sim0 + gi0 * sre0; sre0 = t0;
                float t1 = gr1 * sre1 - gi1 * sim1 + p; sim1 = gr1 * sim1 + gi1 * sre1; sre1 = t1;
            }
            size_t off = (size_t)(k * CH + r) * KTOT + 1024 + m * 32;
            union { bf16 h[2]; uint32_t u; } pr, pi;
            pr.h[0] = __float2bfloat16(sre0); pr.h[1] = __float2bfloat16(sre1);
            pi.h[0] = __float2bfloat16(sim0); pi.h[1] = __float2bfloat16(sim1);
            *(uint32_t*)(A + off + c0)      = pr.u;
            *(uint32_t*)(A + off + 16 + c0) = pi.u;
        }
    }
}

// ---------------- main GEMM: raw partials, optional split-K=2 ----------------
// 128x128 tile, BK=32, global_load_lds width-16, 2-phase loop.
// splitK=2: grid 1024 (4 blocks/CU); split s>>9 -> K-half; dst = p0 (d_out) or p1 (ws).
// splitK=1: grid 512, full K, bias added in epilogue.
__global__ __launch_bounds__(256) void gemm_main(const bf16* __restrict__ A,  // [8192][3072]
                                                 const bf16* __restrict__ B,  // [1024][3072]
                                                 const float* __restrict__ bskip,
                                                 const float* __restrict__ bmix,
                                                 float* __restrict__ p0, float* __restrict__ p1,
                                                 int splitK, int addBias) {
    __shared__ short As[2][128 * 32];
    __shared__ short Bs[2][128 * 32];
    const int tid = threadIdx.x;
    const int lane = tid & 63, wv = tid >> 6;
    const int wm = wv >> 1, wn = wv & 1;

    const int wg = blockIdx.x;
    int split, t;
    if (splitK == 2) { int s = (wg & 7) * 128 + (wg >> 3); split = s >> 9; t = s & 511; }
    else             { int s = (wg & 7) * 64 + (wg >> 3);  split = 0;      t = s; }
    const int row0 = (t >> 3) * 128;     // 64 row tiles
    const int col0 = (t & 7) * 128;      // 8 col tiles
    const int ktBase = split * 48;
    const int NT = (splitK == 2) ? 48 : 96;
    float* dst = split ? p1 : p0;

    const int l4 = lane >> 2;
    const int c8 = (lane & 3) * 8;

    auto stage = [&](int kt, int buf) {
#pragma unroll
        for (int j = 0; j < 2; ++j) {
            int chunk = wv * 2 + j;
            int r = chunk * 16 + l4;
            const bf16* ga = A + (size_t)(row0 + r) * KTOT + kt * 32 + c8;
            const bf16* gb = B + (size_t)(col0 + r) * KTOT + kt * 32 + c8;
            __builtin_amdgcn_global_load_lds(
                (const __attribute__((address_space(1))) void*)ga,
                (__attribute__((address_space(3))) void*)&As[buf][chunk * 512], 16, 0, 0);
            __builtin_amdgcn_global_load_lds(
                (const __attribute__((address_space(1))) void*)gb,
                (__attribute__((address_space(3))) void*)&Bs[buf][chunk * 512], 16, 0, 0);
        }
    };

    f32x4 acc[4][4];
#pragma unroll
    for (int i = 0; i < 4; ++i)
#pragma unroll
        for (int j = 0; j < 4; ++j) acc[i][j] = (f32x4)0.0f;

    stage(ktBase, 0);
    __syncthreads();
    int buf = 0;
    const int lr = lane & 15, lk = (lane >> 4) * 8;
    for (int kk = 0; kk < NT; ++kk) {
        if (kk + 1 < NT) stage(ktBase + kk + 1, buf ^ 1);
        s16x8 af[4], bfr[4];
#pragma unroll
        for (int i = 0; i < 4; ++i)
            af[i] = *(const s16x8*)&As[buf][(wm * 64 + i * 16 + lr) * 32 + lk];
#pragma unroll
        for (int j = 0; j < 4; ++j)
            bfr[j] = *(const s16x8*)&Bs[buf][(wn * 64 + j * 16 + lr) * 32 + lk];
#pragma unroll
        for (int i = 0; i < 4; ++i)
#pragma unroll
            for (int j = 0; j < 4; ++j)
                acc[i][j] = __builtin_amdgcn_mfma_f32_16x16x32_bf16(af[i], bfr[j], acc[i][j], 0, 0, 0);
        __syncthreads();
        buf ^= 1;
    }
    const int lg = lane >> 4;
#pragma unroll
    for (int j = 0; j < 4; ++j) {
        int col = col0 + wn * 64 + j * 16 + lr;
        float bias = addBias ? (bskip[col] + bmix[col]) : 0.0f;
#pragma unroll
        for (int i = 0; i < 4; ++i) {
            int rbase = row0 + wm * 64 + i * 16 + lg * 4;
#pragma unroll
            for (int r = 0; r < 4; ++r)
                dst[(size_t)(rbase + r) * DOUT + col] = acc[i][j][r] + bias;
        }
    }
}

// ---------------- split-K reduce: out = out + p1 + bias ----------------
__global__ void reduce_add(float* __restrict__ out, const float* __restrict__ p1,
                           const float* __restrict__ bskip, const float* __restrict__ bmix) {
    int idx4 = blockIdx.x * 256 + threadIdx.x;   // 2,097,152 total
    int c = (idx4 << 2) & 1023;
    float4 o = *(const float4*)(out + (size_t)idx4 * 4);
    float4 p = *(const float4*)(p1 + (size_t)idx4 * 4);
    o.x += p.x + bskip[c]     + bmix[c];
    o.y += p.y + bskip[c + 1] + bmix[c + 1];
    o.z += p.z + bskip[c + 2] + bmix[c + 2];
    o.w += p.w + bskip[c + 3] + bmix[c + 3];
    *(float4*)(out + (size_t)idx4 * 4) = o;
}

extern "C" void kernel_launch(void* const* d_in, const int* in_sizes, int n_in,
                              void* d_out, int out_size, void* d_ws, size_t ws_size,
                              hipStream_t stream) {
    const float* x        = (const float*)d_in[0];
    const float* state_re = (const float*)d_in[1];
    const float* state_im = (const float*)d_in[2];
    const int*   start    = (const int*)d_in[3];
    const float* W_pre    = (const float*)d_in[5];
    const float* b_pre    = (const float*)d_in[6];
    const float* W_skip   = (const float*)d_in[7];
    const float* b_skip   = (const float*)d_in[8];
    const float* W_mix    = (const float*)d_in[9];
    const float* b_mix    = (const float*)d_in[10];
    const float* a_dec    = (const float*)d_in[11];
    const float* b_freq   = (const float*)d_in[12];

    uint8_t* ws = (uint8_t*)d_ws;
    bf16*  A         = (bf16*)(ws);                 // 50331648
    bf16*  Bc        = (bf16*)(ws + 50331648);      // 6291456
    bf16*  Wp        = (bf16*)(ws + 56623104);      // 131072
    float* pre_raw   = (float*)(ws + 56754176);     // 2097152
    float2* local_end= (float2*)(ws + 58851328);    // 1048576
    float2* carry_in = (float2*)(ws + 59899904);    // 1048576
    int*   reset_any = (int*)(ws + 60948480);       // 512
    float* P1        = (float*)(ws + 60948992);     // 33554432 (split-K partial)
    const size_t ws_needed = 60948992ull + 33554432ull;
    const int splitK = (ws_size >= ws_needed) ? 2 : 1;

    cvt_all<<<dim3((2899968 + 255) / 256), 256, 0, stream>>>(x, W_skip, W_mix, W_pre, A, Bc, Wp);

    pre_scan1<<<dim3(NCHUNK), 256, 0, stream>>>(A, Wp, b_pre, start, a_dec, b_freq,
                                                pre_raw, local_end, reset_any);
    int tail_n = out_size - 8192 * 1024;
    if (tail_n < 0) tail_n = 0;
    if (tail_n > 2048) tail_n = 2048;
    scan_phase2<<<dim3(1), 1024, 0, stream>>>(local_end, reset_any, state_re, state_im, a_dec, b_freq,
                                              carry_in, (float*)d_out + 8192 * 1024, tail_n);
    scan_phase3<<<dim3(NCHUNK), 256, 0, stream>>>(pre_raw, start, a_dec, b_freq, carry_in, A);

    if (splitK == 2) {
        gemm_main<<<dim3(1024), 256, 0, stream>>>(A, Bc, b_skip, b_mix, (float*)d_out, P1, 2, 0);
        reduce_add<<<dim3(8192), 256, 0, stream>>>((float*)d_out, P1, b_skip, b_mix);
    } else {
        gemm_main<<<dim3(512), 256, 0, stream>>>(A, Bc, b_skip, b_mix, (float*)d_out, P1, 1, 1);
    }
}

// Round 6
// 161.257 us; speedup vs baseline: 1.2953x; 1.1541x over previous
//
#include <hip/hip_runtime.h>
#include <hip/hip_bf16.h>
#include <stdint.h>

#define T_LEN 8192
#define DIN   1024
#define DOUT  1024
#define TRACE 64
#define CTX   16
#define KTOT  3072      // DIN + 2*TRACE*CTX
#define CH    64        // scan chunk length
#define NCHUNK 128      // T_LEN / CH

#define AS1 __attribute__((address_space(1)))
#define AS3 __attribute__((address_space(3)))

using bf16 = __hip_bfloat16;
typedef __attribute__((ext_vector_type(4))) float f32x4;
typedef __attribute__((ext_vector_type(8))) short s16x8;

__device__ __forceinline__ void pack4(const float4 v, void* dst) {
    union { bf16 h[4]; uint2 u; } pk;
    pk.h[0] = __float2bfloat16(v.x); pk.h[1] = __float2bfloat16(v.y);
    pk.h[2] = __float2bfloat16(v.z); pk.h[3] = __float2bfloat16(v.w);
    *(uint2*)dst = pk.u;
}

// ---------------- fused f32 -> bf16 conversions (x, W_skip, W_mix, W_pre) ----------------
__global__ void cvt_all(const float* __restrict__ x, const float* __restrict__ Wsk,
                        const float* __restrict__ Wmx, const float* __restrict__ Wpre,
                        bf16* __restrict__ A, bf16* __restrict__ Bc, bf16* __restrict__ Wp) {
    int idx = blockIdx.x * 256 + threadIdx.x;
    if (idx < 2097152) {                       // x: 8192x1024 -> A (ld 3072)
        int r = idx >> 8, c4 = (idx & 255) << 2;
        pack4(*(const float4*)(x + (size_t)r * 1024 + c4), A + (size_t)r * KTOT + c4);
    } else if (idx < 2359296) {                // W_skip: 1024x1024 -> Bc (ld 3072, coff 0)
        int i = idx - 2097152;
        int r = i >> 8, c4 = (i & 255) << 2;
        pack4(*(const float4*)(Wsk + (size_t)r * 1024 + c4), Bc + (size_t)r * KTOT + c4);
    } else if (idx < 2883584) {                // W_mix: 1024x2048 -> Bc (ld 3072, coff 1024)
        int i = idx - 2359296;
        int r = i >> 9, c4 = (i & 511) << 2;
        pack4(*(const float4*)(Wmx + (size_t)r * 2048 + c4), Bc + (size_t)r * KTOT + 1024 + c4);
    } else if (idx < 2899968) {                // W_pre: 64x1024 -> Wp (ld 1024)
        int i = idx - 2883584;
        int r = i >> 8, c4 = (i & 255) << 2;
        pack4(*(const float4*)(Wpre + (size_t)r * 1024 + c4), Wp + (size_t)r * 1024 + c4);
    }
}

// ---------------- fused pre-GEMM + scan phase 1 ----------------
__global__ __launch_bounds__(256) void pre_scan1(
    const bf16* __restrict__ A,     // [8192][KTOT], x part (k<1024)
    const bf16* __restrict__ Wp,    // [64][1024]
    const float* __restrict__ bpre,
    const int* __restrict__ start,
    const float* __restrict__ a, const float* __restrict__ bfreq,
    float* __restrict__ pre_raw,    // [8192][64]
    float2* __restrict__ local_end, // [128][1024]
    int* __restrict__ reset_any) {  // [128]
    __shared__ short As[2][64 * 32];
    __shared__ short Bs[2][64 * 32];
    __shared__ float pn[CH][TRACE + 1];
    __shared__ float rn[CH];
    __shared__ int sf[CH];
    const int tid = threadIdx.x, lane = tid & 63, wv = tid >> 6;
    const int row0 = blockIdx.x * 64;
    const int l4 = lane >> 2, c8 = (lane & 3) * 8;

    auto stage = [&](int kt, int buf) {
        int r = wv * 16 + l4;
        const bf16* ga = A + (size_t)(row0 + r) * KTOT + kt * 32 + c8;
        const bf16* gb = Wp + (size_t)r * 1024 + kt * 32 + c8;
        __builtin_amdgcn_global_load_lds(
            (const AS1 void*)ga, (AS3 void*)&As[buf][wv * 512], 16, 0, 0);
        __builtin_amdgcn_global_load_lds(
            (const AS1 void*)gb, (AS3 void*)&Bs[buf][wv * 512], 16, 0, 0);
    };

    f32x4 acc[4];
#pragma unroll
    for (int j = 0; j < 4; ++j) acc[j] = (f32x4)0.0f;

    stage(0, 0);
    __syncthreads();
    int buf = 0;
    const int lr = lane & 15, lk = (lane >> 4) * 8;
    for (int kt = 0; kt < 32; ++kt) {
        if (kt + 1 < 32) stage(kt + 1, buf ^ 1);
        s16x8 af = *(const s16x8*)&As[buf][(wv * 16 + lr) * 32 + lk];
        s16x8 bfr[4];
#pragma unroll
        for (int j = 0; j < 4; ++j)
            bfr[j] = *(const s16x8*)&Bs[buf][(j * 16 + lr) * 32 + lk];
#pragma unroll
        for (int j = 0; j < 4; ++j)
            acc[j] = __builtin_amdgcn_mfma_f32_16x16x32_bf16(af, bfr[j], acc[j], 0, 0, 0);
        __syncthreads();
        buf ^= 1;
    }
    const int lg = lane >> 4;
#pragma unroll
    for (int j = 0; j < 4; ++j) {
        int col = j * 16 + lr;
        float bias = bpre[col];
#pragma unroll
        for (int r = 0; r < 4; ++r) {
            int rl = wv * 16 + lg * 4 + r;
            float v = acc[j][r] + bias;
            pn[rl][col] = v;
            pre_raw[(size_t)(row0 + rl) * TRACE + col] = v;
        }
    }
    if (tid < CH) sf[tid] = start[row0 + tid];
    __syncthreads();
    if (tid < CH) {
        float s = 0.f;
#pragma unroll
        for (int m = 0; m < TRACE; ++m) { float v = pn[tid][m]; s += v * v; }
        rn[tid] = 1.0f / (1e-6f + sqrtf(s));
        int any = __any(sf[tid] != 0);
        if (tid == 0) reset_any[blockIdx.x] = any;
    }
    __syncthreads();
#pragma unroll
    for (int q = 0; q < 4; ++q) {
        int pair = tid + q * 256;
        int m = pair >> 4, c = pair & 15;
        float am = a[m], th = bfreq[c];
        float e = expf(-fabsf(am));
        float sn, cs; sincosf(th, &sn, &cs);
        float gr = e * cs, gi = e * sn;
        float sre = 0.f, sim = 0.f;
        for (int r = 0; r < CH; ++r) {
            float p = pn[r][m] * rn[r];
            if (sf[r]) { sre = p; sim = 0.f; }
            else { float t = gr * sre - gi * sim + p; sim = gr * sim + gi * sre; sre = t; }
        }
        local_end[(size_t)blockIdx.x * 1024 + pair] = make_float2(sre, sim);
    }
}

// ---------------- scan phase 2: sequential carry, 8-deep prefetch ----------------
// Tail layout: PLANAR — out_tail[0..1023] = re, out_tail[1024..2047] = im.
__global__ void scan_phase2(const float2* __restrict__ local_end, const int* __restrict__ reset_any,
                            const float* __restrict__ state_re, const float* __restrict__ state_im,
                            const float* __restrict__ a, const float* __restrict__ bfreq,
                            float2* __restrict__ carry_in, float* __restrict__ out_tail, int tail_n) {
    const int pair = threadIdx.x;  // 1024 threads
    const int m = pair >> 4, c = pair & 15;
    float am = a[m], th = bfreq[c];
    float e = expf(-64.f * fabsf(am));
    float sn, cs; sincosf(64.f * th, &sn, &cs);
    float gr = e * cs, gi = e * sn;
    float cre = state_re[pair], cim = state_im[pair];

    float2 pf[8]; int rsv[8];
#pragma unroll
    for (int j = 0; j < 8; ++j) { pf[j] = local_end[(size_t)j * 1024 + pair]; rsv[j] = reset_any[j]; }
    for (int kb = 0; kb < NCHUNK; kb += 8) {
        float2 cur[8]; int rs[8];
#pragma unroll
        for (int j = 0; j < 8; ++j) { cur[j] = pf[j]; rs[j] = rsv[j]; }
        if (kb + 8 < NCHUNK) {
#pragma unroll
            for (int j = 0; j < 8; ++j) {
                pf[j]  = local_end[(size_t)(kb + 8 + j) * 1024 + pair];
                rsv[j] = reset_any[kb + 8 + j];
            }
        }
#pragma unroll
        for (int j = 0; j < 8; ++j) {
            carry_in[(size_t)(kb + j) * 1024 + pair] = make_float2(cre, cim);
            if (rs[j]) { cre = cur[j].x; cim = cur[j].y; }
            else {
                float t = gr * cre - gi * cim + cur[j].x;
                cim = gr * cim + gi * cre + cur[j].y;
                cre = t;
            }
        }
    }
    if (pair < tail_n)        out_tail[pair]        = cre;
    if (1024 + pair < tail_n) out_tail[1024 + pair] = cim;
}

// ---------------- scan phase 3: recompute with carry, emit bf16 z_in (4B stores) ----------------
__global__ void scan_phase3(const float* __restrict__ pre_raw, const int* __restrict__ start,
                            const float* __restrict__ a, const float* __restrict__ bfreq,
                            const float2* __restrict__ carry_in, bf16* __restrict__ A) {
    __shared__ float pn[CH][TRACE + 1];
    __shared__ float rn[CH];
    __shared__ int sf[CH];
    const int k = blockIdx.x, tid = threadIdx.x;
    for (int idx = tid; idx < CH * TRACE; idx += 256) {
        int r = idx >> 6, m = idx & 63;
        pn[r][m] = pre_raw[(size_t)(k * CH + r) * TRACE + m];
    }
    if (tid < CH) sf[tid] = start[k * CH + tid];
    __syncthreads();
    if (tid < CH) {
        float s = 0.f;
#pragma unroll
        for (int m = 0; m < TRACE; ++m) { float v = pn[tid][m]; s += v * v; }
        rn[tid] = 1.0f / (1e-6f + sqrtf(s));
    }
    __syncthreads();
#pragma unroll
    for (int q = 0; q < 2; ++q) {
        int p0 = q * 512 + tid * 2;           // even pair: handles (m, c0) and (m, c0+1)
        int m = p0 >> 4, c0 = p0 & 15;
        float am = a[m];
        float e = expf(-fabsf(am));
        float sn0, cs0, sn1, cs1;
        sincosf(bfreq[c0], &sn0, &cs0);
        sincosf(bfreq[c0 + 1], &sn1, &cs1);
        float gr0 = e * cs0, gi0 = e * sn0;
        float gr1 = e * cs1, gi1 = e * sn1;
        float4 ci = *(const float4*)&carry_in[(size_t)k * 1024 + p0];
        float sre0 = ci.x, sim0 = ci.y, sre1 = ci.z, sim1 = ci.w;
        for (int r = 0; r < CH; ++r) {
            float p = pn[r][m] * rn[r];
            if (sf[r]) { sre0 = p; sim0 = 0.f; sre1 = p; sim1 = 0.f; }
            else {
                float t0 = gr0 * sre0 - gi0 * sim0 + p; sim0 = gr0 * sim0 + gi0 * sre0; sre0 = t0;
                float t1 = gr1 * sre1 - gi1 * sim1 + p; sim1 = gr1 * sim1 + gi1 * sre1; sre1 = t1;
            }
            size_t off = (size_t)(k * CH + r) * KTOT + 1024 + m * 32;
            union { bf16 h[2]; uint32_t u; } pr, pi;
            pr.h[0] = __float2bfloat16(sre0); pr.h[1] = __float2bfloat16(sre1);
            pi.h[0] = __float2bfloat16(sim0); pi.h[1] = __float2bfloat16(sim1);
            *(uint32_t*)(A + off + c0)      = pr.u;
            *(uint32_t*)(A + off + 16 + c0) = pi.u;
        }
    }
}

// ---------------- main GEMM: out = [x|z] @ [W_skip|W_mix]^T + bias ----------------
// BM=256 BN=128 BK=64, 512 thr (8 waves 4Mx2N, 64x64/wave), grid 256 = 1 block/CU.
// 3-deep K-tile pipeline: counted vmcnt(12) (never 0 until tail), raw barriers,
// both-sides XOR swizzle (u ^= row&7 per 16B unit) for conflict-spread ds_read_b128.
__global__ __launch_bounds__(512) void gemm_main(const bf16* __restrict__ A,  // [8192][3072]
                                                 const bf16* __restrict__ B,  // [1024][3072]
                                                 const float* __restrict__ bskip,
                                                 const float* __restrict__ bmix,
                                                 float* __restrict__ out) {   // [8192][1024]
    __shared__ short As[3][256 * 64];   // 96 KB
    __shared__ short Bs[3][128 * 64];   // 48 KB
    const int tid = threadIdx.x;
    const int lane = tid & 63, wv = tid >> 6;
    const int wm = wv >> 1, wn = wv & 1;
    const int wg = blockIdx.x;
    const int row0 = (wg >> 3) * 256;    // 32 row tiles
    const int col0 = (wg & 7) * 128;     // 8 col tiles (one per XCD -> B-panel L2-resident)

    const int rl8 = lane >> 3;           // row within 8-row chunk
    const int u8  = lane & 7;            // 16B unit within 128B row

    auto stage = [&](int kt, int bsel) {
#pragma unroll
        for (int j = 0; j < 4; ++j) {    // A: wave covers 32 rows in 4 calls
            int r = wv * 32 + j * 8 + rl8;
            int ksw = (u8 ^ (r & 7)) << 3;     // pre-swizzled global k-offset (shorts)
            const bf16* ga = A + (size_t)(row0 + r) * KTOT + kt * 64 + ksw;
            __builtin_amdgcn_global_load_lds((const AS1 void*)ga,
                (AS3 void*)&As[bsel][(wv * 32 + j * 8) * 64], 16, 0, 0);
        }
#pragma unroll
        for (int j = 0; j < 2; ++j) {    // B: wave covers 16 rows in 2 calls
            int r = wv * 16 + j * 8 + rl8;
            int ksw = (u8 ^ (r & 7)) << 3;
            const bf16* gb = B + (size_t)(col0 + r) * KTOT + kt * 64 + ksw;
            __builtin_amdgcn_global_load_lds((const AS1 void*)gb,
                (AS3 void*)&Bs[bsel][(wv * 16 + j * 8) * 64], 16, 0, 0);
        }
    };

    f32x4 acc[4][4];
#pragma unroll
    for (int i = 0; i < 4; ++i)
#pragma unroll
        for (int j = 0; j < 4; ++j) acc[i][j] = (f32x4)0.0f;

    stage(0, 0); stage(1, 1); stage(2, 2);   // 18 vm-ops/wave in flight

    const int lr = lane & 15, hi = lane >> 4;
    int sw[2];                                // swizzled unit offsets (shorts) per k-half
    sw[0] = ((hi)     ^ (lr & 7)) << 3;
    sw[1] = ((4 + hi) ^ (lr & 7)) << 3;

    int bsel = 0;
    const int NT = KTOT / 64;  // 48
    for (int t = 0; t < NT; ++t) {
        if (t < NT - 2)      asm volatile("s_waitcnt vmcnt(12)" ::: "memory");
        else if (t == NT-2)  asm volatile("s_waitcnt vmcnt(6)" ::: "memory");
        else                 asm volatile("s_waitcnt vmcnt(0)" ::: "memory");
        __builtin_amdgcn_s_barrier();

        s16x8 af[4][2], bfr[4][2];
#pragma unroll
        for (int kk = 0; kk < 2; ++kk) {
#pragma unroll
            for (int i = 0; i < 4; ++i)
                af[i][kk] = *(const s16x8*)&As[bsel][(wm * 64 + i * 16 + lr) * 64 + sw[kk]];
#pragma unroll
            for (int j = 0; j < 4; ++j)
                bfr[j][kk] = *(const s16x8*)&Bs[bsel][(wn * 64 + j * 16 + lr) * 64 + sw[kk]];
        }
        __builtin_amdgcn_s_setprio(1);
#pragma unroll
        for (int kk = 0; kk < 2; ++kk)
#pragma unroll
            for (int i = 0; i < 4; ++i)
#pragma unroll
                for (int j = 0; j < 4; ++j)
                    acc[i][j] = __builtin_amdgcn_mfma_f32_16x16x32_bf16(af[i][kk], bfr[j][kk], acc[i][j], 0, 0, 0);
        __builtin_amdgcn_s_setprio(0);

        asm volatile("s_waitcnt lgkmcnt(0)" ::: "memory");  // my ds_reads done before others restage
        __builtin_amdgcn_s_barrier();
        if (t + 3 < NT) stage(t + 3, bsel);
        bsel = (bsel == 2) ? 0 : bsel + 1;
    }

    const int lg = lane >> 4;
#pragma unroll
    for (int j = 0; j < 4; ++j) {
        int col = col0 + wn * 64 + j * 16 + lr;
        float bias = bskip[col] + bmix[col];
#pragma unroll
        for (int i = 0; i < 4; ++i) {
            int rbase = row0 + wm * 64 + i * 16 + lg * 4;
#pragma unroll
            for (int r = 0; r < 4; ++r)
                out[(size_t)(rbase + r) * DOUT + col] = acc[i][j][r] + bias;
        }
    }
}

extern "C" void kernel_launch(void* const* d_in, const int* in_sizes, int n_in,
                              void* d_out, int out_size, void* d_ws, size_t ws_size,
                              hipStream_t stream) {
    const float* x        = (const float*)d_in[0];
    const float* state_re = (const float*)d_in[1];
    const float* state_im = (const float*)d_in[2];
    const int*   start    = (const int*)d_in[3];
    const float* W_pre    = (const float*)d_in[5];
    const float* b_pre    = (const float*)d_in[6];
    const float* W_skip   = (const float*)d_in[7];
    const float* b_skip   = (const float*)d_in[8];
    const float* W_mix    = (const float*)d_in[9];
    const float* b_mix    = (const float*)d_in[10];
    const float* a_dec    = (const float*)d_in[11];
    const float* b_freq   = (const float*)d_in[12];

    uint8_t* ws = (uint8_t*)d_ws;
    bf16*  A         = (bf16*)(ws);                 // 50331648
    bf16*  Bc        = (bf16*)(ws + 50331648);      // 6291456
    bf16*  Wp        = (bf16*)(ws + 56623104);      // 131072
    float* pre_raw   = (float*)(ws + 56754176);     // 2097152
    float2* local_end= (float2*)(ws + 58851328);    // 1048576
    float2* carry_in = (float2*)(ws + 59899904);    // 1048576
    int*   reset_any = (int*)(ws + 60948480);       // 512

    cvt_all<<<dim3((2899968 + 255) / 256), 256, 0, stream>>>(x, W_skip, W_mix, W_pre, A, Bc, Wp);

    pre_scan1<<<dim3(NCHUNK), 256, 0, stream>>>(A, Wp, b_pre, start, a_dec, b_freq,
                                                pre_raw, local_end, reset_any);
    int tail_n = out_size - 8192 * 1024;
    if (tail_n < 0) tail_n = 0;
    if (tail_n > 2048) tail_n = 2048;
    scan_phase2<<<dim3(1), 1024, 0, stream>>>(local_end, reset_any, state_re, state_im, a_dec, b_freq,
                                              carry_in, (float*)d_out + 8192 * 1024, tail_n);
    scan_phase3<<<dim3(NCHUNK), 256, 0, stream>>>(pre_raw, start, a_dec, b_freq, carry_in, A);

    gemm_main<<<dim3(256), 512, 0, stream>>>(A, Bc, b_skip, b_mix, (float*)d_out);
}

// Round 7
// 128.670 us; speedup vs baseline: 1.6233x; 1.2533x over previous
//
#include <hip/hip_runtime.h>
#include <hip/hip_bf16.h>
#include <stdint.h>

#define T_LEN 8192
#define DIN   1024
#define DOUT  1024
#define TRACE 64
#define CTX   16
#define KTOT  3072      // DIN + 2*TRACE*CTX
#define CH    64        // scan chunk length
#define NCHUNK 128      // T_LEN / CH

#define AS1 __attribute__((address_space(1)))
#define AS3 __attribute__((address_space(3)))

using bf16 = __hip_bfloat16;
typedef __attribute__((ext_vector_type(4))) float f32x4;
typedef __attribute__((ext_vector_type(8))) short s16x8;

__device__ __forceinline__ void pack4(const float4 v, void* dst) {
    union { bf16 h[4]; uint2 u; } pk;
    pk.h[0] = __float2bfloat16(v.x); pk.h[1] = __float2bfloat16(v.y);
    pk.h[2] = __float2bfloat16(v.z); pk.h[3] = __float2bfloat16(v.w);
    *(uint2*)dst = pk.u;
}

// ---------------- fused f32 -> bf16 conversions (x, W_skip, W_mix, W_pre) ----------------
__global__ void cvt_all(const float* __restrict__ x, const float* __restrict__ Wsk,
                        const float* __restrict__ Wmx, const float* __restrict__ Wpre,
                        bf16* __restrict__ A, bf16* __restrict__ Bc, bf16* __restrict__ Wp) {
    int idx = blockIdx.x * 256 + threadIdx.x;
    if (idx < 2097152) {                       // x: 8192x1024 -> A (ld 3072)
        int r = idx >> 8, c4 = (idx & 255) << 2;
        pack4(*(const float4*)(x + (size_t)r * 1024 + c4), A + (size_t)r * KTOT + c4);
    } else if (idx < 2359296) {                // W_skip: 1024x1024 -> Bc (ld 3072, coff 0)
        int i = idx - 2097152;
        int r = i >> 8, c4 = (i & 255) << 2;
        pack4(*(const float4*)(Wsk + (size_t)r * 1024 + c4), Bc + (size_t)r * KTOT + c4);
    } else if (idx < 2883584) {                // W_mix: 1024x2048 -> Bc (ld 3072, coff 1024)
        int i = idx - 2359296;
        int r = i >> 9, c4 = (i & 511) << 2;
        pack4(*(const float4*)(Wmx + (size_t)r * 2048 + c4), Bc + (size_t)r * KTOT + 1024 + c4);
    } else if (idx < 2899968) {                // W_pre: 64x1024 -> Wp (ld 1024)
        int i = idx - 2883584;
        int r = i >> 8, c4 = (i & 255) << 2;
        pack4(*(const float4*)(Wpre + (size_t)r * 1024 + c4), Wp + (size_t)r * 1024 + c4);
    }
}

// ---------------- fused pre-GEMM + scan phase 1 ----------------
__global__ __launch_bounds__(256) void pre_scan1(
    const bf16* __restrict__ A,     // [8192][KTOT], x part (k<1024)
    const bf16* __restrict__ Wp,    // [64][1024]
    const float* __restrict__ bpre,
    const int* __restrict__ start,
    const float* __restrict__ a, const float* __restrict__ bfreq,
    float* __restrict__ pre_raw,    // [8192][64]
    float2* __restrict__ local_end, // [128][1024]
    int* __restrict__ reset_any) {  // [128]
    __shared__ short As[2][64 * 32];
    __shared__ short Bs[2][64 * 32];
    __shared__ float pn[CH][TRACE + 1];
    __shared__ float rn[CH];
    __shared__ int sf[CH];
    const int tid = threadIdx.x, lane = tid & 63, wv = tid >> 6;
    const int row0 = blockIdx.x * 64;
    const int l4 = lane >> 2, c8 = (lane & 3) * 8;

    auto stage = [&](int kt, int buf) {
        int r = wv * 16 + l4;
        const bf16* ga = A + (size_t)(row0 + r) * KTOT + kt * 32 + c8;
        const bf16* gb = Wp + (size_t)r * 1024 + kt * 32 + c8;
        __builtin_amdgcn_global_load_lds(
            (const AS1 void*)ga, (AS3 void*)&As[buf][wv * 512], 16, 0, 0);
        __builtin_amdgcn_global_load_lds(
            (const AS1 void*)gb, (AS3 void*)&Bs[buf][wv * 512], 16, 0, 0);
    };

    f32x4 acc[4];
#pragma unroll
    for (int j = 0; j < 4; ++j) acc[j] = (f32x4)0.0f;

    stage(0, 0);
    __syncthreads();
    int buf = 0;
    const int lr = lane & 15, lk = (lane >> 4) * 8;
    for (int kt = 0; kt < 32; ++kt) {
        if (kt + 1 < 32) stage(kt + 1, buf ^ 1);
        s16x8 af = *(const s16x8*)&As[buf][(wv * 16 + lr) * 32 + lk];
        s16x8 bfr[4];
#pragma unroll
        for (int j = 0; j < 4; ++j)
            bfr[j] = *(const s16x8*)&Bs[buf][(j * 16 + lr) * 32 + lk];
#pragma unroll
        for (int j = 0; j < 4; ++j)
            acc[j] = __builtin_amdgcn_mfma_f32_16x16x32_bf16(af, bfr[j], acc[j], 0, 0, 0);
        __syncthreads();
        buf ^= 1;
    }
    const int lg = lane >> 4;
#pragma unroll
    for (int j = 0; j < 4; ++j) {
        int col = j * 16 + lr;
        float bias = bpre[col];
#pragma unroll
        for (int r = 0; r < 4; ++r) {
            int rl = wv * 16 + lg * 4 + r;
            float v = acc[j][r] + bias;
            pn[rl][col] = v;
            pre_raw[(size_t)(row0 + rl) * TRACE + col] = v;
        }
    }
    if (tid < CH) sf[tid] = start[row0 + tid];
    __syncthreads();
    if (tid < CH) {
        float s = 0.f;
#pragma unroll
        for (int m = 0; m < TRACE; ++m) { float v = pn[tid][m]; s += v * v; }
        rn[tid] = 1.0f / (1e-6f + sqrtf(s));
        int any = __any(sf[tid] != 0);
        if (tid == 0) reset_any[blockIdx.x] = any;
    }
    __syncthreads();
#pragma unroll
    for (int q = 0; q < 4; ++q) {
        int pair = tid + q * 256;
        int m = pair >> 4, c = pair & 15;
        float am = a[m], th = bfreq[c];
        float e = expf(-fabsf(am));
        float sn, cs; sincosf(th, &sn, &cs);
        float gr = e * cs, gi = e * sn;
        float sre = 0.f, sim = 0.f;
        for (int r = 0; r < CH; ++r) {
            float p = pn[r][m] * rn[r];
            if (sf[r]) { sre = p; sim = 0.f; }
            else { float t = gr * sre - gi * sim + p; sim = gr * sim + gi * sre; sre = t; }
        }
        local_end[(size_t)blockIdx.x * 1024 + pair] = make_float2(sre, sim);
    }
}

// ---------------- scan phase 2: sequential carry, 8-deep prefetch, 16 blocks x 64 thr ----------------
// Tail layout: PLANAR — out_tail[0..1023] = re, out_tail[1024..2047] = im.
__global__ void scan_phase2(const float2* __restrict__ local_end, const int* __restrict__ reset_any,
                            const float* __restrict__ state_re, const float* __restrict__ state_im,
                            const float* __restrict__ a, const float* __restrict__ bfreq,
                            float2* __restrict__ carry_in, float* __restrict__ out_tail, int tail_n) {
    const int pair = blockIdx.x * 64 + threadIdx.x;  // 16*64 = 1024
    const int m = pair >> 4, c = pair & 15;
    float am = a[m], th = bfreq[c];
    float e = expf(-64.f * fabsf(am));
    float sn, cs; sincosf(64.f * th, &sn, &cs);
    float gr = e * cs, gi = e * sn;
    float cre = state_re[pair], cim = state_im[pair];

    float2 pf[8]; int rsv[8];
#pragma unroll
    for (int j = 0; j < 8; ++j) { pf[j] = local_end[(size_t)j * 1024 + pair]; rsv[j] = reset_any[j]; }
    for (int kb = 0; kb < NCHUNK; kb += 8) {
        float2 cur[8]; int rs[8];
#pragma unroll
        for (int j = 0; j < 8; ++j) { cur[j] = pf[j]; rs[j] = rsv[j]; }
        if (kb + 8 < NCHUNK) {
#pragma unroll
            for (int j = 0; j < 8; ++j) {
                pf[j]  = local_end[(size_t)(kb + 8 + j) * 1024 + pair];
                rsv[j] = reset_any[kb + 8 + j];
            }
        }
#pragma unroll
        for (int j = 0; j < 8; ++j) {
            carry_in[(size_t)(kb + j) * 1024 + pair] = make_float2(cre, cim);
            if (rs[j]) { cre = cur[j].x; cim = cur[j].y; }
            else {
                float t = gr * cre - gi * cim + cur[j].x;
                cim = gr * cim + gi * cre + cur[j].y;
                cre = t;
            }
        }
    }
    if (pair < tail_n)        out_tail[pair]        = cre;
    if (1024 + pair < tail_n) out_tail[1024 + pair] = cim;
}

// ---------------- scan phase 3: recompute with carry, emit bf16 z_in (4B stores) ----------------
__global__ void scan_phase3(const float* __restrict__ pre_raw, const int* __restrict__ start,
                            const float* __restrict__ a, const float* __restrict__ bfreq,
                            const float2* __restrict__ carry_in, bf16* __restrict__ A) {
    __shared__ float pn[CH][TRACE + 1];
    __shared__ float rn[CH];
    __shared__ int sf[CH];
    const int k = blockIdx.x, tid = threadIdx.x;
    for (int idx = tid; idx < CH * TRACE; idx += 256) {
        int r = idx >> 6, m = idx & 63;
        pn[r][m] = pre_raw[(size_t)(k * CH + r) * TRACE + m];
    }
    if (tid < CH) sf[tid] = start[k * CH + tid];
    __syncthreads();
    if (tid < CH) {
        float s = 0.f;
#pragma unroll
        for (int m = 0; m < TRACE; ++m) { float v = pn[tid][m]; s += v * v; }
        rn[tid] = 1.0f / (1e-6f + sqrtf(s));
    }
    __syncthreads();
#pragma unroll
    for (int q = 0; q < 2; ++q) {
        int p0 = q * 512 + tid * 2;           // even pair: handles (m, c0) and (m, c0+1)
        int m = p0 >> 4, c0 = p0 & 15;
        float am = a[m];
        float e = expf(-fabsf(am));
        float sn0, cs0, sn1, cs1;
        sincosf(bfreq[c0], &sn0, &cs0);
        sincosf(bfreq[c0 + 1], &sn1, &cs1);
        float gr0 = e * cs0, gi0 = e * sn0;
        float gr1 = e * cs1, gi1 = e * sn1;
        float4 ci = *(const float4*)&carry_in[(size_t)k * 1024 + p0];
        float sre0 = ci.x, sim0 = ci.y, sre1 = ci.z, sim1 = ci.w;
        for (int r = 0; r < CH; ++r) {
            float p = pn[r][m] * rn[r];
            if (sf[r]) { sre0 = p; sim0 = 0.f; sre1 = p; sim1 = 0.f; }
            else {
                float t0 = gr0 * sre0 - gi0 * sim0 + p; sim0 = gr0 * sim0 + gi0 * sre0; sre0 = t0;
                float t1 = gr1 * sre1 - gi1 * sim1 + p; sim1 = gr1 * sim1 + gi1 * sre1; sre1 = t1;
            }
            size_t off = (size_t)(k * CH + r) * KTOT + 1024 + m * 32;
            union { bf16 h[2]; uint32_t u; } pr, pi;
            pr.h[0] = __float2bfloat16(sre0); pr.h[1] = __float2bfloat16(sre1);
            pi.h[0] = __float2bfloat16(sim0); pi.h[1] = __float2bfloat16(sim1);
            *(uint32_t*)(A + off + c0)      = pr.u;
            *(uint32_t*)(A + off + 16 + c0) = pi.u;
        }
    }
}

// ---------------- main GEMM: out = [x|z] @ [W_skip|W_mix]^T + bias ----------------
// BM=256 BN=128 BK=64, 512 thr (8 waves 4Mx2N), grid 256 = 1 block/CU.
// Single-barrier 3-buffer stage-ahead-2 pipeline: per iter {vmcnt(6), barrier,
// stage(t+2) into buf consumed at t-1, ds_read buf t%3, 32 MFMA}. XOR-swizzled
// LDS (both-sides involution, conflict-free). XCD x owns row-panels [4x,4x+4) x all cols.
__global__ __launch_bounds__(512) void gemm_main(const bf16* __restrict__ A,  // [8192][3072]
                                                 const bf16* __restrict__ B,  // [1024][3072]
                                                 const float* __restrict__ bskip,
                                                 const float* __restrict__ bmix,
                                                 float* __restrict__ out) {   // [8192][1024]
    __shared__ short As[3][256 * 64];   // 96 KB
    __shared__ short Bs[3][128 * 64];   // 48 KB
    const int tid = threadIdx.x;
    const int lane = tid & 63, wv = tid >> 6;
    const int wm = wv >> 1, wn = wv & 1;
    const int wg = blockIdx.x;
    // HW round-robins wg across 8 XCDs: XCD = wg&7. Give XCD x row-panels [4x,4x+4) x 8 cols.
    const int xcd = wg & 7, idx = wg >> 3;           // idx 0..31
    const int row0 = (xcd * 4 + (idx >> 3)) * 256;   // 32 row tiles
    const int col0 = (idx & 7) * 128;                // 8 col tiles

    const int rl8 = lane >> 3;           // row within 8-row chunk
    const int u8  = lane & 7;            // 16B unit within 128B row

    auto stage = [&](int kt, int bsel) {
#pragma unroll
        for (int j = 0; j < 4; ++j) {    // A: wave covers 32 rows in 4 calls
            int r = wv * 32 + j * 8 + rl8;
            int ksw = (u8 ^ (r & 7)) << 3;     // pre-swizzled global k-offset (shorts)
            const bf16* ga = A + (size_t)(row0 + r) * KTOT + kt * 64 + ksw;
            __builtin_amdgcn_global_load_lds((const AS1 void*)ga,
                (AS3 void*)&As[bsel][(wv * 32 + j * 8) * 64], 16, 0, 0);
        }
#pragma unroll
        for (int j = 0; j < 2; ++j) {    // B: wave covers 16 rows in 2 calls
            int r = wv * 16 + j * 8 + rl8;
            int ksw = (u8 ^ (r & 7)) << 3;
            const bf16* gb = B + (size_t)(col0 + r) * KTOT + kt * 64 + ksw;
            __builtin_amdgcn_global_load_lds((const AS1 void*)gb,
                (AS3 void*)&Bs[bsel][(wv * 16 + j * 8) * 64], 16, 0, 0);
        }
    };

    f32x4 acc[4][4];
#pragma unroll
    for (int i = 0; i < 4; ++i)
#pragma unroll
        for (int j = 0; j < 4; ++j) acc[i][j] = (f32x4)0.0f;

    stage(0, 0); stage(1, 1);            // 12 vm-ops/wave in flight

    const int lr = lane & 15, hi = lane >> 4;
    int sw[2];                           // swizzled unit offsets (shorts) per k-half
    sw[0] = ((hi)     ^ (lr & 7)) << 3;
    sw[1] = ((4 + hi) ^ (lr & 7)) << 3;

    const int NT = KTOT / 64;  // 48 (multiple of 3)
    auto kstep = [&](int t, int bsel) __attribute__((always_inline)) {
        if (t < NT - 1) asm volatile("s_waitcnt vmcnt(6)" ::: "memory");
        else            asm volatile("s_waitcnt vmcnt(0)" ::: "memory");
        __builtin_amdgcn_s_barrier();
        // restage buffer consumed at t-1 (all waves' t-1 ds_reads complete:
        // their MFMA operand lgkmcnt waits preceded the barrier)
        if (t + 2 < NT) { int b2 = bsel + 2; if (b2 >= 3) b2 -= 3; stage(t + 2, b2); }
        s16x8 af[4][2], bfr[4][2];
#pragma unroll
        for (int kk = 0; kk < 2; ++kk) {
#pragma unroll
            for (int i = 0; i < 4; ++i)
                af[i][kk] = *(const s16x8*)&As[bsel][(wm * 64 + i * 16 + lr) * 64 + sw[kk]];
#pragma unroll
            for (int j = 0; j < 4; ++j)
                bfr[j][kk] = *(const s16x8*)&Bs[bsel][(wn * 64 + j * 16 + lr) * 64 + sw[kk]];
        }
        __builtin_amdgcn_s_setprio(1);
#pragma unroll
        for (int kk = 0; kk < 2; ++kk)
#pragma unroll
            for (int i = 0; i < 4; ++i)
#pragma unroll
                for (int j = 0; j < 4; ++j)
                    acc[i][j] = __builtin_amdgcn_mfma_f32_16x16x32_bf16(af[i][kk], bfr[j][kk], acc[i][j], 0, 0, 0);
        __builtin_amdgcn_s_setprio(0);
    };

    for (int tt = 0; tt < NT; tt += 3) { // bsel compile-time per copy
        kstep(tt,     0);
        kstep(tt + 1, 1);
        kstep(tt + 2, 2);
    }

    const int lg = lane >> 4;
#pragma unroll
    for (int j = 0; j < 4; ++j) {
        int col = col0 + wn * 64 + j * 16 + lr;
        float bias = bskip[col] + bmix[col];
#pragma unroll
        for (int i = 0; i < 4; ++i) {
            int rbase = row0 + wm * 64 + i * 16 + lg * 4;
#pragma unroll
            for (int r = 0; r < 4; ++r)
                out[(size_t)(rbase + r) * DOUT + col] = acc[i][j][r] + bias;
        }
    }
}

extern "C" void kernel_launch(void* const* d_in, const int* in_sizes, int n_in,
                              void* d_out, int out_size, void* d_ws, size_t ws_size,
                              hipStream_t stream) {
    const float* x        = (const float*)d_in[0];
    const float* state_re = (const float*)d_in[1];
    const float* state_im = (const float*)d_in[2];
    const int*   start    = (const int*)d_in[3];
    const float* W_pre    = (const float*)d_in[5];
    const float* b_pre    = (const float*)d_in[6];
    const float* W_skip   = (const float*)d_in[7];
    const float* b_skip   = (const float*)d_in[8];
    const float* W_mix    = (const float*)d_in[9];
    const float* b_mix    = (const float*)d_in[10];
    const float* a_dec    = (const float*)d_in[11];
    const float* b_freq   = (const float*)d_in[12];

    uint8_t* ws = (uint8_t*)d_ws;
    bf16*  A         = (bf16*)(ws);                 // 50331648
    bf16*  Bc        = (bf16*)(ws + 50331648);      // 6291456
    bf16*  Wp        = (bf16*)(ws + 56623104);      // 131072
    float* pre_raw   = (float*)(ws + 56754176);     // 2097152
    float2* local_end= (float2*)(ws + 58851328);    // 1048576
    float2* carry_in = (float2*)(ws + 59899904);    // 1048576
    int*   reset_any = (int*)(ws + 60948480);       // 512

    cvt_all<<<dim3((2899968 + 255) / 256), 256, 0, stream>>>(x, W_skip, W_mix, W_pre, A, Bc, Wp);

    pre_scan1<<<dim3(NCHUNK), 256, 0, stream>>>(A, Wp, b_pre, start, a_dec, b_freq,
                                                pre_raw, local_end, reset_any);
    int tail_n = out_size - 8192 * 1024;
    if (tail_n < 0) tail_n = 0;
    if (tail_n > 2048) tail_n = 2048;
    scan_phase2<<<dim3(16), 64, 0, stream>>>(local_end, reset_any, state_re, state_im, a_dec, b_freq,
                                             carry_in, (float*)d_out + 8192 * 1024, tail_n);
    scan_phase3<<<dim3(NCHUNK), 256, 0, stream>>>(pre_raw, start, a_dec, b_freq, carry_in, A);

    gemm_main<<<dim3(256), 512, 0, stream>>>(A, Bc, b_skip, b_mix, (float*)d_out);
}